// Round 5
// baseline (289.153 us; speedup 1.0000x reference)
//
#include <hip/hip_runtime.h>
#include <math.h>

#define N 4096
#define DQ 128
#define DIN 64
#define DC 32
#define NT 9          // 9 n-tiles of 16: cols 0..127 = v, col 128 = p (z), 129..143 = 0
#define PSTRIDE 144
#define NIT (N / 16)  // 256 i-tiles

typedef __attribute__((ext_vector_type(8))) short short8;
typedef __attribute__((ext_vector_type(4))) float f32x4;

__device__ __forceinline__ unsigned short f2bf(float x) {
  unsigned u = __float_as_uint(x);
  return (unsigned short)((u + 0x7fffu + ((u >> 16) & 1u)) >> 16);
}
__device__ __forceinline__ float bf2f(unsigned short b) {
  return __uint_as_float(((unsigned)b) << 16);
}
// B-fragment swizzle: element (j,d) of V' -> flat index in frag-ordered array.
// Frag layout (16x16x32 bf16 B): lane holds B[k=quad*8+jj][n=lane&15].
__device__ __forceinline__ size_t swz(int j, int d) {
  const int kt = j >> 5, quad = (j & 31) >> 3, jj = j & 7;
  const int lane = quad * 16 + (d & 15), nt = d >> 4;
  return ((size_t)(kt * NT + nt) * 64 + lane) * 8 + jj;
}

// ---- shared epilogue: p*(h@W_av+b_av) -> bf16 hi/lo swizzled, + z column ----
__device__ __forceinline__ void v_phase(const float* hs_row, float p,
    const float* __restrict__ W_av_k, const float* __restrict__ b_av_k,
    int j, int d4, unsigned short* __restrict__ Vhi, unsigned short* __restrict__ Vlo) {
  float a[4] = {b_av_k[d4], b_av_k[d4 + 1], b_av_k[d4 + 2], b_av_k[d4 + 3]};
  for (int c = 0; c < DQ; ++c) {
    const float hv = hs_row[c];
    const float4 w = *(const float4*)&W_av_k[c * DQ + d4];
    a[0] += hv * w.x; a[1] += hv * w.y; a[2] += hv * w.z; a[3] += hv * w.w;
  }
#pragma unroll
  for (int e = 0; e < 4; ++e) {
    const float val = p * a[e];
    const unsigned short hi = f2bf(val);
    const unsigned short lo = f2bf(val - bf2f(hi));
    const size_t ix = swz(j, d4 + e);
    Vhi[ix] = hi; Vlo[ix] = lo;
  }
  if (d4 == 0) {                       // z column: p at d=128, zeros 129..143
    const unsigned short phi = f2bf(p);
    const unsigned short plo = f2bf(p - bf2f(phi));
    const size_t ix = swz(j, 128);
    Vhi[ix] = phi; Vlo[ix] = plo;
    for (int dd = 129; dd < 144; ++dd) {
      const size_t iz = swz(j, dd);
      Vhi[iz] = 0; Vlo[iz] = 0;
    }
  }
}

// ---- round 0: encode + sa + p + V' fused (8 rows per block) ----
__global__ __launch_bounds__(256) void kVS0(const float* __restrict__ x,
    const float* __restrict__ comms, const float* __restrict__ W_enc,
    const float* __restrict__ b_enc, const float* __restrict__ W_ad_k,
    const float* __restrict__ wa, const float* __restrict__ W_av_k,
    const float* __restrict__ b_av_k,
    unsigned short* __restrict__ Vhi, unsigned short* __restrict__ Vlo) {
  __shared__ float xs[8][96];
  __shared__ float hs[8][DQ];
  __shared__ float u[DQ];
  __shared__ float pb[8];
  const int tid = threadIdx.x;
  const int blk = blockIdx.x;
  if (tid < 128) {
    const float4 v = *(const float4*)&x[(size_t)blk * 8 * DIN + tid * 4];
    const int idx = tid * 4, r = idx >> 6, c = idx & 63;
    xs[r][c] = v.x; xs[r][c + 1] = v.y; xs[r][c + 2] = v.z; xs[r][c + 3] = v.w;
  } else if (tid < 192) {
    const int t = tid - 128;
    const float4 v = *(const float4*)&comms[(size_t)blk * 8 * DC + t * 4];
    const int idx = t * 4, r = idx >> 5, c = idx & 31;
    xs[r][64 + c] = v.x; xs[r][64 + c + 1] = v.y; xs[r][64 + c + 2] = v.z; xs[r][64 + c + 3] = v.w;
  }
  if (tid < DQ) {
    float s = 0.f;
    const float* wrow = &W_ad_k[tid * DQ];
    for (int q = 0; q < DQ; ++q) s += wrow[q] * wa[q];
    u[tid] = s;
  }
  __syncthreads();
  const int r = tid >> 5;
  const int c32 = tid & 31;
  const int d4 = c32 * 4;
  const int j = blk * 8 + r;
  {
    float a0 = b_enc[d4], a1 = b_enc[d4 + 1], a2 = b_enc[d4 + 2], a3 = b_enc[d4 + 3];
    for (int c = 0; c < 96; ++c) {
      const float hv = xs[r][c];
      const float4 w = *(const float4*)&W_enc[c * DQ + d4];
      a0 += hv * w.x; a1 += hv * w.y; a2 += hv * w.z; a3 += hv * w.w;
    }
    hs[r][d4] = a0; hs[r][d4 + 1] = a1; hs[r][d4 + 2] = a2; hs[r][d4 + 3] = a3;
  }
  __syncthreads();
  float part = 0.f;
  for (int c = c32; c < DQ; c += 32) part += hs[r][c] * u[c];
#pragma unroll
  for (int m = 16; m > 0; m >>= 1) part += __shfl_xor(part, m, 32);
  if (c32 == 0) pb[r] = __expf(part);
  __syncthreads();
  v_phase(hs[r], pb[r], W_av_k, b_av_k, j, d4, Vhi, Vlo);
}

// ---- rounds 1,2: P-reduce -> h + sa + p + V' fused (8 rows per block) ----
__global__ __launch_bounds__(256) void kVSR(const float* __restrict__ P,
    const float* __restrict__ W_ad_k, const float* __restrict__ wa,
    const float* __restrict__ W_av_k, const float* __restrict__ b_av_k,
    unsigned short* __restrict__ Vhi, unsigned short* __restrict__ Vlo,
    int ksplit) {
  __shared__ float hs[8][DQ];
  __shared__ float u[DQ];
  __shared__ float pb[8];
  const int tid = threadIdx.x;
  const int r = tid >> 5;
  const int c32 = tid & 31;
  const int d4 = c32 * 4;
  const int j = blockIdx.x * 8 + r;
  if (tid < DQ) {
    float s = 0.f;
    const float* wrow = &W_ad_k[tid * DQ];
    for (int q = 0; q < DQ; ++q) s += wrow[q] * wa[q];
    u[tid] = s;
  }
  float4 num = {0.f, 0.f, 0.f, 0.f};
  float den = 0.f;
  for (int s = 0; s < ksplit; ++s) {
    const float* b = &P[((size_t)s * N + j) * PSTRIDE];
    const float4 v = *(const float4*)&b[d4];
    num.x += v.x; num.y += v.y; num.z += v.z; num.w += v.w;
    den += b[128];
  }
  const float inv = 1.f / den;
  hs[r][d4] = num.x * inv; hs[r][d4 + 1] = num.y * inv;
  hs[r][d4 + 2] = num.z * inv; hs[r][d4 + 3] = num.w * inv;
  __syncthreads();
  float part = 0.f;
  for (int c = c32; c < DQ; c += 32) part += hs[r][c] * u[c];
#pragma unroll
  for (int m = 16; m > 0; m >>= 1) part += __shfl_xor(part, m, 32);
  if (c32 == 0) pb[r] = __expf(part);
  __syncthreads();
  v_phase(hs[r], pb[r], W_av_k, b_av_k, j, d4, Vhi, Vlo);
}

// ---- MFMA GEMM: P[s][i][d] = sum_j E[j][i] * V'[j,d], bf16 split-3 ----------
// One wave per block; each wave owns 2 i-tiles (32 rows) for register B reuse.
// PRE=false (round 0): A from strided trans + exp + split, store frags to Ehi/Elo.
// PRE=true (rounds 1,2): A = two coalesced short8 loads per tile from Ehi/Elo.
template <bool PRE>
__global__ __launch_bounds__(64) void kGemmM(const float* __restrict__ trans,
    unsigned short* __restrict__ Ehi, unsigned short* __restrict__ Elo,
    const unsigned short* __restrict__ Vhi, const unsigned short* __restrict__ Vlo,
    float* __restrict__ P, int kchunk) {
  const int lane = threadIdx.x;
  const int quad = lane >> 4, l15 = lane & 15;
  const int it0 = blockIdx.x * 2;                // two adjacent i-tiles
  const int i0 = it0 * 16;
  const int k0 = blockIdx.y * kchunk;
  const int nsteps = kchunk >> 5;

  f32x4 acc[2][NT];
#pragma unroll
  for (int ti = 0; ti < 2; ++ti)
#pragma unroll
    for (int nt = 0; nt < NT; ++nt) acc[ti][nt] = (f32x4){0.f, 0.f, 0.f, 0.f};

  float araw[2][8];
  short8 pah[2], pal[2];
  if (PRE) {
    const size_t kt = (size_t)(k0 >> 5);
#pragma unroll
    for (int ti = 0; ti < 2; ++ti) {
      const size_t ix = ((kt * NIT + it0 + ti) * 64 + lane) * 8;
      pah[ti] = *(const short8*)(Ehi + ix);
      pal[ti] = *(const short8*)(Elo + ix);
    }
  } else {
#pragma unroll
    for (int ti = 0; ti < 2; ++ti) {
      const float* aptr = trans + (size_t)(k0 + quad * 8) * N + i0 + ti * 16 + l15;
#pragma unroll
      for (int jj = 0; jj < 8; ++jj) araw[ti][jj] = aptr[(size_t)jj * N];
    }
  }

  for (int t = 0; t < nsteps; ++t) {
    const size_t kt = (size_t)(k0 >> 5) + t;
    short8 ah[2], al[2];
    if (PRE) {
      ah[0] = pah[0]; ah[1] = pah[1]; al[0] = pal[0]; al[1] = pal[1];
      if (t + 1 < nsteps) {
#pragma unroll
        for (int ti = 0; ti < 2; ++ti) {
          const size_t ix = (((kt + 1) * NIT + it0 + ti) * 64 + lane) * 8;
          pah[ti] = *(const short8*)(Ehi + ix);
          pal[ti] = *(const short8*)(Elo + ix);
        }
      }
    } else {
      float anext[2][8];
      if (t + 1 < nsteps) {
#pragma unroll
        for (int ti = 0; ti < 2; ++ti) {
          const float* ap2 = trans + (size_t)(k0 + (t + 1) * 32 + quad * 8) * N + i0 + ti * 16 + l15;
#pragma unroll
          for (int jj = 0; jj < 8; ++jj) anext[ti][jj] = ap2[(size_t)jj * N];
        }
      }
#pragma unroll
      for (int ti = 0; ti < 2; ++ti) {
        unsigned short hb[8], lb[8];
#pragma unroll
        for (int jj = 0; jj < 8; ++jj) {
          const float e = __expf(araw[ti][jj]);
          hb[jj] = f2bf(e);
          lb[jj] = f2bf(e - bf2f(hb[jj]));
        }
        ah[ti] = (short8){(short)hb[0], (short)hb[1], (short)hb[2], (short)hb[3],
                          (short)hb[4], (short)hb[5], (short)hb[6], (short)hb[7]};
        al[ti] = (short8){(short)lb[0], (short)lb[1], (short)lb[2], (short)lb[3],
                          (short)lb[4], (short)lb[5], (short)lb[6], (short)lb[7]};
        const size_t ix = ((kt * NIT + it0 + ti) * 64 + lane) * 8;
        *(short8*)(Ehi + ix) = ah[ti];
        *(short8*)(Elo + ix) = al[ti];
#pragma unroll
        for (int jj = 0; jj < 8; ++jj) araw[ti][jj] = anext[ti][jj];
      }
    }
    const unsigned short* bh = Vhi + (kt * NT * 64 + lane) * 8;
    const unsigned short* bl = Vlo + (kt * NT * 64 + lane) * 8;
#pragma unroll
    for (int nt = 0; nt < NT; ++nt) {
      const short8 bhv = *(const short8*)(bh + (size_t)nt * 512);
      const short8 blv = *(const short8*)(bl + (size_t)nt * 512);
#pragma unroll
      for (int ti = 0; ti < 2; ++ti) {
        acc[ti][nt] = __builtin_amdgcn_mfma_f32_16x16x32_bf16(ah[ti], bhv, acc[ti][nt], 0, 0, 0);
        acc[ti][nt] = __builtin_amdgcn_mfma_f32_16x16x32_bf16(ah[ti], blv, acc[ti][nt], 0, 0, 0);
        acc[ti][nt] = __builtin_amdgcn_mfma_f32_16x16x32_bf16(al[ti], bhv, acc[ti][nt], 0, 0, 0);
      }
    }
  }
  // C layout: col = lane&15, row = quad*4 + reg
  float* Pb = P + (size_t)blockIdx.y * N * PSTRIDE;
#pragma unroll
  for (int ti = 0; ti < 2; ++ti) {
#pragma unroll
    for (int nt = 0; nt < NT; ++nt) {
#pragma unroll
      for (int r = 0; r < 4; ++r) {
        const int i = i0 + ti * 16 + quad * 4 + r;
        Pb[(size_t)i * PSTRIDE + nt * 16 + l15] = acc[ti][nt][r];
      }
    }
  }
}

// ---- final: out[i] = (sum_d num[i][d] W_dec[d]) / den + b_dec ----
__global__ __launch_bounds__(256) void kOutR(const float* __restrict__ P,
    const float* __restrict__ W_dec, const float* __restrict__ b_dec,
    const int* __restrict__ mask, float* __restrict__ out, int ksplit) {
  __shared__ float red[256];
  const int tid = threadIdx.x;
  const int d = tid & 127;
  const int i = blockIdx.x * 2 + (tid >> 7);
  float num = 0.f, den = 0.f;
  for (int s = 0; s < ksplit; ++s) {
    const float* b = &P[((size_t)s * N + i) * PSTRIDE];
    num += b[d];
    den += b[128];
  }
  red[tid] = num * W_dec[d];
  __syncthreads();
  for (int st = 64; st > 0; st >>= 1) {
    if (d < st) red[tid] += red[tid + st];
    __syncthreads();
  }
  if (d == 0) out[i] = (mask[i] == 0) ? -INFINITY : red[tid] / den + b_dec[0];
}

extern "C" void kernel_launch(void* const* d_in, const int* in_sizes, int n_in,
                              void* d_out, int out_size, void* d_ws, size_t ws_size,
                              hipStream_t stream) {
  (void)in_sizes; (void)n_in; (void)out_size;
  const float* x     = (const float*)d_in[0];
  const float* comms = (const float*)d_in[1];
  const float* trans = (const float*)d_in[2];
  const int*   mask  = (const int*)d_in[3];
  const float* W_enc = (const float*)d_in[4];
  const float* b_enc = (const float*)d_in[5];
  const float* W_ad  = (const float*)d_in[6];
  // d_in[7]=b_ad, d_in[9]=b_att cancel inside the row softmax
  const float* w_att = (const float*)d_in[8];
  const float* W_av  = (const float*)d_in[10];
  const float* b_av  = (const float*)d_in[11];
  const float* W_dec = (const float*)d_in[12];
  const float* b_dec = (const float*)d_in[13];
  float* out         = (float*)d_out;

  char* ws = (char*)d_ws;
  unsigned short* Vhi = (unsigned short*)ws;  ws += (size_t)N * PSTRIDE * 2;
  unsigned short* Vlo = (unsigned short*)ws;  ws += (size_t)N * PSTRIDE * 2;
  unsigned short* Ehi = (unsigned short*)ws;  ws += (size_t)N * N * 2;
  unsigned short* Elo = (unsigned short*)ws;  ws += (size_t)N * N * 2;
  float* P = (float*)ws;
  const size_t fixedB = (size_t)N * PSTRIDE * 4 + (size_t)N * N * 4;
  const size_t perB   = (size_t)N * PSTRIDE * 4;          // one P split (fp32)
  const int ksplit = (ws_size >= fixedB + 16 * perB) ? 16 : 8;
  const int kchunk = N / ksplit;

  for (int k = 0; k < 3; ++k) {
    const float* W_ad_k = W_ad + (size_t)k * DQ * DQ;
    const float* wa     = w_att + (size_t)k * 2 * DQ;
    const float* W_av_k = W_av + (size_t)k * DQ * DQ;
    const float* b_av_k = b_av + (size_t)k * DQ;
    if (k == 0) {
      kVS0<<<N / 8, 256, 0, stream>>>(x, comms, W_enc, b_enc, W_ad_k, wa,
                                      W_av_k, b_av_k, Vhi, Vlo);
      kGemmM<false><<<dim3(N / 32, ksplit), 64, 0, stream>>>(
          trans, Ehi, Elo, Vhi, Vlo, P, kchunk);
    } else {
      kVSR<<<N / 8, 256, 0, stream>>>(P, W_ad_k, wa, W_av_k, b_av_k,
                                      Vhi, Vlo, ksplit);
      kGemmM<true><<<dim3(N / 32, ksplit), 64, 0, stream>>>(
          trans, Ehi, Elo, Vhi, Vlo, P, kchunk);
    }
  }
  kOutR<<<N / 2, 256, 0, stream>>>(P, W_dec, b_dec, mask, out, ksplit);
}